// Round 9
// baseline (327.315 us; speedup 1.0000x reference)
//
#include <hip/hip_runtime.h>

typedef __attribute__((ext_vector_type(8))) _Float16 f16x8;
typedef __attribute__((ext_vector_type(4))) float f32x4;

#define B_SZ   16
#define N_SEQ  4096
#define M_CTX  77
#define M_PAD  96
#define NH     8

__device__ __forceinline__ _Float16 f2h(float x) { return (_Float16)x; }

// async global->LDS, 16B per lane. dst = wave-uniform base; HW writes
// dst + lane*16. Source address is per-lane (pre-swizzled by caller).
__device__ __forceinline__ void gload16(const void* g, void* l) {
    __builtin_amdgcn_global_load_lds(
        (const __attribute__((address_space(1))) unsigned int*)g,
        (__attribute__((address_space(3))) unsigned int*)l, 16, 0, 0);
}

// ---- DPP 16-lane butterfly reductions (XOR masks {1,2,7,15} span 0..15) ----
template<int C>
__device__ __forceinline__ float dppf(float x) {
    union { float f; int i; } u, v;
    u.f = x;
    v.i = __builtin_amdgcn_mov_dpp(u.i, C, 0xF, 0xF, true);
    return v.f;
}
__device__ __forceinline__ float rmax16(float x) {
    x = fmaxf(x, dppf<0xB1>(x));    // quad_perm(1,0,3,2)  xor 1
    x = fmaxf(x, dppf<0x4E>(x));    // quad_perm(2,3,0,1)  xor 2
    x = fmaxf(x, dppf<0x141>(x));   // row_half_mirror     xor 7
    x = fmaxf(x, dppf<0x140>(x));   // row_mirror          xor 15
    return x;
}
__device__ __forceinline__ float rsum16(float x) {
    x += dppf<0xB1>(x);
    x += dppf<0x4E>(x);
    x += dppf<0x141>(x);
    x += dppf<0x140>(x);
    return x;
}

// ---------------------------------------------------------------------------
// prep: W [K][512] fp32 -> WT [512][K] f16 (LDS-tiled transpose).
// Wq gets the 1/sqrt(D_HEAD)=0.125 softmax scale folded in.
// ---------------------------------------------------------------------------
__global__ __launch_bounds__(256)
void prep(const float* __restrict__ Wq, const float* __restrict__ Wk,
          const float* __restrict__ Wv, const float* __restrict__ Wo,
          _Float16* __restrict__ WqT, _Float16* __restrict__ WkT,
          _Float16* __restrict__ WvT, _Float16* __restrict__ WoT)
{
    __shared__ float t[32][33];
    const float* W; _Float16* WT; int K; float scale = 1.0f;
    switch (blockIdx.z) {
        case 0:  W = Wq; WT = WqT; K = 512; scale = 0.125f; break;
        case 1:  W = Wk; WT = WkT; K = 768; break;
        case 2:  W = Wv; WT = WvT; K = 768; break;
        default: W = Wo; WT = WoT; K = 512; break;
    }
    const int ky = blockIdx.y;
    if (ky * 32 >= K) return;
    const int nx = blockIdx.x;
    const int tr = threadIdx.x >> 5, tc = threadIdx.x & 31;
#pragma unroll
    for (int i = 0; i < 4; ++i) {
        int kr = tr + i * 8;
        t[kr][tc] = W[(size_t)(ky * 32 + kr) * 512 + nx * 32 + tc];
    }
    __syncthreads();
#pragma unroll
    for (int i = 0; i < 4; ++i) {
        int nr = tr + i * 8;
        WT[(size_t)(nx * 32 + nr) * K + ky * 32 + tc] = f2h(t[tc][nr] * scale);
    }
}

// ---------------------------------------------------------------------------
// kv_proj: writes K and V in BANK-SWIZZLED global layouts:
//   Kswz[bh][m][ ((d>>3)^(m&7))*8 + (d&7) ]   m in 0..95 (zeros >= 77)
//   Vswz[bh][d][ ((m>>3)^(d&7))*8 + (m&7) ]   rows of 128 f16 (slots 0..11 used)
// grid (8 h, 16 b, 2 kv); block 256 = 4 waves
// ---------------------------------------------------------------------------
__global__ __launch_bounds__(256)
void kv_proj(const float* __restrict__ cond, const _Float16* __restrict__ WkT,
             const _Float16* __restrict__ WvT, _Float16* __restrict__ Kswz,
             _Float16* __restrict__ Vswz)
{
    const int tid = threadIdx.x;
    const int l = tid & 63, w = tid >> 6;
    const int lrow = l & 15, lk = l >> 4;
    const int h = blockIdx.x, b = blockIdx.y, which = blockIdx.z;
    const _Float16* WT = which ? WvT : WkT;
    const float* cb = cond + (size_t)b * M_CTX * 768;

    f32x4 acc[5];
#pragma unroll
    for (int i = 0; i < 5; ++i)
#pragma unroll
        for (int e = 0; e < 4; ++e) acc[i][e] = 0.f;

    const int n = h * 64 + w * 16 + lrow;
    for (int kk = 0; kk < 24; ++kk) {
        f16x8 bfrag = *(const f16x8*)(WT + (size_t)n * 768 + kk * 32 + lk * 8);
#pragma unroll
        for (int rt = 0; rt < 5; ++rt) {
            int m = rt * 16 + lrow;
            f16x8 afrag;
#pragma unroll
            for (int j = 0; j < 8; ++j) afrag[j] = (_Float16)0.f;
            if (m < M_CTX) {
                const float* a = cb + (size_t)m * 768 + kk * 32 + lk * 8;
                float4 f0 = *(const float4*)a;
                float4 f1 = *(const float4*)(a + 4);
                afrag[0] = f2h(f0.x); afrag[1] = f2h(f0.y);
                afrag[2] = f2h(f0.z); afrag[3] = f2h(f0.w);
                afrag[4] = f2h(f1.x); afrag[5] = f2h(f1.y);
                afrag[6] = f2h(f1.z); afrag[7] = f2h(f1.w);
            }
            acc[rt] = __builtin_amdgcn_mfma_f32_16x16x32_f16(afrag, bfrag, acc[rt], 0, 0, 0);
        }
    }

    const int bh = b * NH + h;
    const int d = w * 16 + lrow;
    const int dhi = d >> 3, dlo = d & 7;
    if (which == 0) {
        _Float16* Kb = Kswz + (size_t)bh * (M_PAD * 64);
#pragma unroll
        for (int rt = 0; rt < 5; ++rt)
#pragma unroll
            for (int r = 0; r < 4; ++r) {
                int m = rt * 16 + lk * 4 + r;
                Kb[m * 64 + ((dhi ^ (m & 7)) * 8) + dlo] = f2h(acc[rt][r]);
            }
#pragma unroll
        for (int r = 0; r < 4; ++r) {
            int m = 80 + lk * 4 + r;
            Kb[m * 64 + ((dhi ^ (m & 7)) * 8) + dlo] = (_Float16)0.f;
        }
    } else {
        _Float16* Vb = Vswz + (size_t)bh * (64 * 128);
#pragma unroll
        for (int rt = 0; rt < 5; ++rt)
#pragma unroll
            for (int r = 0; r < 4; ++r) {
                int m = rt * 16 + lk * 4 + r;
                Vb[d * 128 + (((m >> 3) ^ dlo) * 8) + (m & 7)] = f2h(acc[rt][r]);
            }
#pragma unroll
        for (int r = 0; r < 4; ++r) {
            int m = 80 + lk * 4 + r;
            Vb[d * 128 + (((m >> 3) ^ dlo) * 8) + (m & 7)] = (_Float16)0.f;
        }
    }
}

// ---------------------------------------------------------------------------
// gemm_qd: Qf[65536][512] f16 = x(fp32) @ WqT -- BARRIER-FREE, LDS-FREE.
// MFMA fragments gathered directly from global (wave = 16 rows x 64B lines,
// L2/L3-hot for both re-read patterns); fp32->f16 cvt fused on the A path.
// No __syncthreads anywhere => compiler pipelines loads across K freely.
// 128x128 tile, 4 waves (2x2 of 64x64). XCD-chunked swizzle (2048 = 8*256).
// ---------------------------------------------------------------------------
__global__ __launch_bounds__(256)
void gemm_qd(const float* __restrict__ X, const _Float16* __restrict__ BT,
             _Float16* __restrict__ C)
{
    const int bid = blockIdx.x;
    const int wg = (bid & 7) * 256 + (bid >> 3);
    const int rb = wg >> 2, cb = wg & 3;
    const size_t row0 = (size_t)rb * 128;
    const int col0 = cb * 128;

    const int tid = threadIdx.x;
    const int l = tid & 63, w = tid >> 6;
    const int wy = w >> 1, wx = w & 1;
    const int lrow = l & 15, lk = l >> 4;

    f32x4 acc[4][4];
#pragma unroll
    for (int i = 0; i < 4; ++i)
#pragma unroll
        for (int j = 0; j < 4; ++j)
#pragma unroll
            for (int e = 0; e < 4; ++e) acc[i][j][e] = 0.f;

    const float*    ab = X  + (row0 + wy * 64 + lrow) * 512 + lk * 8;
    const _Float16* bb = BT + (size_t)(col0 + wx * 64 + lrow) * 512 + lk * 8;

#pragma unroll 4
    for (int kt = 0; kt < 16; ++kt) {      // K = 512, 32 per step
        f16x8 af[4], bf[4];
#pragma unroll
        for (int mt = 0; mt < 4; ++mt) {
            const float* a = ab + (size_t)mt * 16 * 512 + kt * 32;
            float4 f0 = *(const float4*)a;
            float4 f1 = *(const float4*)(a + 4);
            f16x8 v;
            v[0] = f2h(f0.x); v[1] = f2h(f0.y); v[2] = f2h(f0.z); v[3] = f2h(f0.w);
            v[4] = f2h(f1.x); v[5] = f2h(f1.y); v[6] = f2h(f1.z); v[7] = f2h(f1.w);
            af[mt] = v;
        }
#pragma unroll
        for (int nt = 0; nt < 4; ++nt)
            bf[nt] = *(const f16x8*)(bb + (size_t)nt * 16 * 512 + kt * 32);
#pragma unroll
        for (int mt = 0; mt < 4; ++mt)
#pragma unroll
            for (int nt = 0; nt < 4; ++nt)
                acc[mt][nt] = __builtin_amdgcn_mfma_f32_16x16x32_f16(af[mt], bf[nt], acc[mt][nt], 0, 0, 0);
    }

#pragma unroll
    for (int mt = 0; mt < 4; ++mt)
#pragma unroll
        for (int nt = 0; nt < 4; ++nt)
#pragma unroll
            for (int r = 0; r < 4; ++r) {
                size_t row = row0 + wy * 64 + mt * 16 + lk * 4 + r;
                int col = col0 + wx * 64 + nt * 16 + lrow;
                C[row * 512 + col] = f2h(acc[mt][nt][r]);
            }
}

// ---------------------------------------------------------------------------
// attn (R3-proven): one block = one (b,h) x 256 Q-rows. K,V staged to LDS
// once via gload16 (swizzled layouts pre-baked in global). 4 waves x 64 rows.
// DPP softmax reductions, deferred 1/sum in the O epilogue.
// grid (16 chunks, 8 h, 16 b); block 256.
// ---------------------------------------------------------------------------
__global__ __launch_bounds__(256)
void attn(const _Float16* __restrict__ Q, const _Float16* __restrict__ Kswz,
          const _Float16* __restrict__ Vswz, _Float16* __restrict__ AO)
{
    __shared__ _Float16 Ks[M_PAD * 64];    // 12KB: row m, slot s at s^(m&7)
    __shared__ _Float16 Vs[64 * 128];      // 16KB: row d, slot s at s^(d&7)
    __shared__ _Float16 Pl[4][16][104];    // 13KB: per-wave P tile

    const int tid = threadIdx.x;
    const int l = tid & 63, w = tid >> 6;
    const int lrow = l & 15, lk = l >> 4;
    const int chunk = blockIdx.x, h = blockIdx.y, b = blockIdx.z;
    const int bh = b * NH + h;

    {
        const _Float16* Kg = Kswz + (size_t)bh * (M_PAD * 64);
        const _Float16* Vg = Vswz + (size_t)bh * (64 * 128);
#pragma unroll
        for (int i = 0; i < 3; ++i) {
            int c = w * 3 + i;
            gload16(Kg + c * 512 + l * 8, Ks + c * 512);
        }
#pragma unroll
        for (int i = 0; i < 4; ++i) {
            int c = w * 4 + i;
            gload16(Vg + c * 512 + l * 8, Vs + c * 512);
        }
    }

    const size_t row0 = (size_t)b * N_SEQ + chunk * 256 + w * 64;
    f16x8 af[4][2];
    {
        const _Float16* Qb = Q + (row0 + lrow) * 512 + h * 64 + lk * 8;
#pragma unroll
        for (int mt = 0; mt < 4; ++mt)
#pragma unroll
            for (int kk = 0; kk < 2; ++kk)
                af[mt][kk] = *(const f16x8*)(Qb + (size_t)mt * 16 * 512 + kk * 32);
    }

    for (int idx = l; idx < 256; idx += 64)
        Pl[w][idx >> 4][80 + (idx & 15)] = (_Float16)0.f;

    __syncthreads();   // drains vmcnt: K/V in LDS

    const bool m4ok = (lrow < 13);
    const int kswz = lrow & 7;

#pragma unroll
    for (int mt = 0; mt < 4; ++mt) {
        f32x4 s[5];
#pragma unroll
        for (int i = 0; i < 5; ++i)
#pragma unroll
            for (int e = 0; e < 4; ++e) s[i][e] = 0.f;
#pragma unroll
        for (int kk = 0; kk < 2; ++kk)
#pragma unroll
            for (int ct = 0; ct < 5; ++ct) {
                f16x8 kf = *(const f16x8*)&Ks[(ct * 16 + lrow) * 64 + (((kk * 4 + lk) ^ kswz) * 8)];
                s[ct] = __builtin_amdgcn_mfma_f32_16x16x32_f16(af[mt][kk], kf, s[ct], 0, 0, 0);
            }

        float rinv[4];
#pragma unroll
        for (int r = 0; r < 4; ++r) {
            float v0 = s[0][r], v1 = s[1][r], v2 = s[2][r], v3 = s[3][r], v4 = s[4][r];
            float mx = fmaxf(fmaxf(v0, v1), fmaxf(v2, v3));
            mx = fmaxf(mx, m4ok ? v4 : -1e30f);
            mx = rmax16(mx);
            float e0 = __expf(v0 - mx), e1 = __expf(v1 - mx);
            float e2 = __expf(v2 - mx), e3 = __expf(v3 - mx);
            float e4 = m4ok ? __expf(v4 - mx) : 0.f;
            float sum = ((e0 + e1) + (e2 + e3)) + e4;
            sum = rsum16(sum);
            rinv[r] = 1.0f / sum;
            int prow = lk * 4 + r;
            Pl[w][prow][lrow]      = f2h(e0);
            Pl[w][prow][16 + lrow] = f2h(e1);
            Pl[w][prow][32 + lrow] = f2h(e2);
            Pl[w][prow][48 + lrow] = f2h(e3);
            Pl[w][prow][64 + lrow] = f2h(e4);
        }

        f32x4 o[4];
#pragma unroll
        for (int i = 0; i < 4; ++i)
#pragma unroll
            for (int e2 = 0; e2 < 4; ++e2) o[i][e2] = 0.f;
#pragma unroll
        for (int kk = 0; kk < 3; ++kk) {
            f16x8 pa = *(const f16x8*)&Pl[w][lrow][kk * 32 + lk * 8];
#pragma unroll
            for (int ctd = 0; ctd < 4; ++ctd) {
                f16x8 vf = *(const f16x8*)&Vs[(ctd * 16 + lrow) * 128 + (((kk * 4 + lk) ^ kswz) * 8)];
                o[ctd] = __builtin_amdgcn_mfma_f32_16x16x32_f16(pa, vf, o[ctd], 0, 0, 0);
            }
        }

        const size_t rw = row0 + mt * 16 + lk * 4;
#pragma unroll
        for (int ctd = 0; ctd < 4; ++ctd)
#pragma unroll
            for (int r = 0; r < 4; ++r)
                AO[(rw + r) * 512 + h * 64 + ctd * 16 + lrow] = f2h(o[ctd][r] * rinv[r]);
    }
}

// ---------------------------------------------------------------------------
// gemm_o (R3-proven gemm512<1>): out fp32 = AO f16 @ WoT + bo.
// 128x128 tile, BK=64, global_load_lds w/ pre-swizzled source, 4 waves.
// ---------------------------------------------------------------------------
__global__ __launch_bounds__(256)
void gemm_o(const _Float16* __restrict__ A, const _Float16* __restrict__ BT,
            float* __restrict__ Cv, const float* __restrict__ bias)
{
    __shared__ _Float16 As[128 * 64];
    __shared__ _Float16 Bs[128 * 64];

    const int bid = blockIdx.x;
    const int wg = (bid & 7) * 256 + (bid >> 3);
    const int rb = wg >> 2;
    const int cb = wg & 3;
    const size_t row0 = (size_t)rb * 128;
    const int col0 = cb * 128;

    const int tid = threadIdx.x;
    const int l = tid & 63;
    const int w = tid >> 6;
    const int wy = w >> 1, wx = w & 1;
    const int lrow = l & 15, lk = l >> 4;

    f32x4 acc[4][4];
#pragma unroll
    for (int i = 0; i < 4; ++i)
#pragma unroll
        for (int j = 0; j < 4; ++j)
#pragma unroll
            for (int e = 0; e < 4; ++e) acc[i][j][e] = 0.f;

    const int srow_in_seg = l >> 3;
    const int sslot = (l & 7) ^ (srow_in_seg & 7);
    const _Float16* a_src0 = A + (row0 + (size_t)(w * 32 + srow_in_seg)) * 512 + sslot * 8;
    const _Float16* b_src0 = BT + ((size_t)(col0 + w * 32 + srow_in_seg)) * 512 + sslot * 8;

    for (int kt = 0; kt < 8; ++kt) {
        const _Float16* ak = a_src0 + kt * 64;
        const _Float16* bk = b_src0 + kt * 64;
#pragma unroll
        for (int s = 0; s < 4; ++s) {
            gload16(ak + (size_t)s * 8 * 512, As + (w * 4 + s) * 512);
            gload16(bk + (size_t)s * 8 * 512, Bs + (w * 4 + s) * 512);
        }
        __syncthreads();

#pragma unroll
        for (int kk = 0; kk < 2; ++kk) {
            f16x8 af[4], bf[4];
#pragma unroll
            for (int mt = 0; mt < 4; ++mt) {
                int R = wy * 64 + mt * 16 + lrow;
                int p = (kk * 4 + lk) ^ (lrow & 7);
                af[mt] = *(const f16x8*)&As[R * 64 + p * 8];
            }
#pragma unroll
            for (int nt = 0; nt < 4; ++nt) {
                int R = wx * 64 + nt * 16 + lrow;
                int p = (kk * 4 + lk) ^ (lrow & 7);
                bf[nt] = *(const f16x8*)&Bs[R * 64 + p * 8];
            }
#pragma unroll
            for (int mt = 0; mt < 4; ++mt)
#pragma unroll
                for (int nt = 0; nt < 4; ++nt)
                    acc[mt][nt] = __builtin_amdgcn_mfma_f32_16x16x32_f16(af[mt], bf[nt], acc[mt][nt], 0, 0, 0);
        }
        __syncthreads();
    }

#pragma unroll
    for (int mt = 0; mt < 4; ++mt)
#pragma unroll
        for (int nt = 0; nt < 4; ++nt)
#pragma unroll
            for (int r = 0; r < 4; ++r) {
                size_t row = row0 + wy * 64 + mt * 16 + lk * 4 + r;
                int col = col0 + wx * 64 + nt * 16 + lrow;
                Cv[row * 512 + col] = acc[mt][nt][r] + bias[col];
            }
}

// ---------------------------------------------------------------------------
extern "C" void kernel_launch(void* const* d_in, const int* in_sizes, int n_in,
                              void* d_out, int out_size, void* d_ws, size_t ws_size,
                              hipStream_t stream)
{
    (void)in_sizes; (void)n_in; (void)out_size; (void)ws_size;
    const float* x    = (const float*)d_in[0];
    const float* cond = (const float*)d_in[1];
    const float* Wq   = (const float*)d_in[2];
    const float* Wk   = (const float*)d_in[3];
    const float* Wv   = (const float*)d_in[4];
    const float* Wo   = (const float*)d_in[5];
    const float* bo   = (const float*)d_in[6];

    char* ws = (char*)d_ws;
    _Float16* WqT  = (_Float16*)(ws);                        // 524288
    _Float16* WoT  = (_Float16*)(ws + 524288);               // 524288
    _Float16* Kswz = (_Float16*)(ws + 1048576);              // 1572864
    _Float16* Vswz = (_Float16*)(ws + 2621440);              // 2097152
    _Float16* AO   = (_Float16*)(ws + 4718592);              // 67108864
    // WkT/WvT alias AO's head: consumed by kv_proj BEFORE attn writes AO
    _Float16* WkT  = (_Float16*)(ws + 4718592);              // 786432
    _Float16* WvT  = (_Float16*)(ws + 4718592 + 786432);     // 786432
    // total ws: 71,827,456 bytes (same as previous rounds)
    _Float16* Qf   = (_Float16*)d_out;                       // f16 Q scratch in d_out
                                                             // (dead before gemm_o writes)

    prep<<<dim3(16, 24, 4), 256, 0, stream>>>(Wq, Wk, Wv, Wo, WqT, WkT, WvT, WoT);
    kv_proj<<<dim3(8, 16, 2), 256, 0, stream>>>(cond, WkT, WvT, Kswz, Vswz);
    gemm_qd<<<dim3(2048), 256, 0, stream>>>(x, WqT, Qf);
    attn<<<dim3(16, 8, 16), 256, 0, stream>>>(Qf, Kswz, Vswz, AO);
    gemm_o<<<dim3(2048), 256, 0, stream>>>(AO, WoT, (float*)d_out, bo);
}

// Round 10
// 249.161 us; speedup vs baseline: 1.3137x; 1.3137x over previous
//
#include <hip/hip_runtime.h>

typedef __attribute__((ext_vector_type(8))) _Float16 f16x8;
typedef __attribute__((ext_vector_type(4))) float f32x4;

#define B_SZ   16
#define N_SEQ  4096
#define M_CTX  77
#define M_PAD  96
#define NH     8

__device__ __forceinline__ _Float16 f2h(float x) { return (_Float16)x; }

// async global->LDS, 16B per lane. dst = wave-uniform base; HW writes
// dst + lane*16. Source address is per-lane (pre-swizzled by caller).
__device__ __forceinline__ void gload16(const void* g, void* l) {
    __builtin_amdgcn_global_load_lds(
        (const __attribute__((address_space(1))) unsigned int*)g,
        (__attribute__((address_space(3))) unsigned int*)l, 16, 0, 0);
}

// ---- DPP 16-lane butterfly reductions (XOR masks {1,2,7,15} span 0..15) ----
template<int C>
__device__ __forceinline__ float dppf(float x) {
    union { float f; int i; } u, v;
    u.f = x;
    v.i = __builtin_amdgcn_mov_dpp(u.i, C, 0xF, 0xF, true);
    return v.f;
}
__device__ __forceinline__ float rmax16(float x) {
    x = fmaxf(x, dppf<0xB1>(x));    // quad_perm(1,0,3,2)  xor 1
    x = fmaxf(x, dppf<0x4E>(x));    // quad_perm(2,3,0,1)  xor 2
    x = fmaxf(x, dppf<0x141>(x));   // row_half_mirror     xor 7
    x = fmaxf(x, dppf<0x140>(x));   // row_mirror          xor 15
    return x;
}
__device__ __forceinline__ float rsum16(float x) {
    x += dppf<0xB1>(x);
    x += dppf<0x4E>(x);
    x += dppf<0x141>(x);
    x += dppf<0x140>(x);
    return x;
}

// ---------------------------------------------------------------------------
// prep: W [K][512] fp32 -> WT [512][K] f16 (LDS-tiled transpose).
// Wq gets the 1/sqrt(D_HEAD)=0.125 softmax scale folded in.
// ---------------------------------------------------------------------------
__global__ __launch_bounds__(256)
void prep(const float* __restrict__ Wq, const float* __restrict__ Wk,
          const float* __restrict__ Wv, const float* __restrict__ Wo,
          _Float16* __restrict__ WqT, _Float16* __restrict__ WkT,
          _Float16* __restrict__ WvT, _Float16* __restrict__ WoT)
{
    __shared__ float t[32][33];
    const float* W; _Float16* WT; int K; float scale = 1.0f;
    switch (blockIdx.z) {
        case 0:  W = Wq; WT = WqT; K = 512; scale = 0.125f; break;
        case 1:  W = Wk; WT = WkT; K = 768; break;
        case 2:  W = Wv; WT = WvT; K = 768; break;
        default: W = Wo; WT = WoT; K = 512; break;
    }
    const int ky = blockIdx.y;
    if (ky * 32 >= K) return;
    const int nx = blockIdx.x;
    const int tr = threadIdx.x >> 5, tc = threadIdx.x & 31;
#pragma unroll
    for (int i = 0; i < 4; ++i) {
        int kr = tr + i * 8;
        t[kr][tc] = W[(size_t)(ky * 32 + kr) * 512 + nx * 32 + tc];
    }
    __syncthreads();
#pragma unroll
    for (int i = 0; i < 4; ++i) {
        int nr = tr + i * 8;
        WT[(size_t)(nx * 32 + nr) * K + ky * 32 + tc] = f2h(t[tc][nr] * scale);
    }
}

// ---------------------------------------------------------------------------
// kv_proj: writes K and V in BANK-SWIZZLED global layouts:
//   Kswz[bh][m][ ((d>>3)^(m&7))*8 + (d&7) ]   m in 0..95 (zeros >= 77)
//   Vswz[bh][d][ ((m>>3)^(d&7))*8 + (m&7) ]   rows of 128 f16 (slots 0..11 used)
// grid (8 h, 16 b, 2 kv); block 256 = 4 waves
// ---------------------------------------------------------------------------
__global__ __launch_bounds__(256)
void kv_proj(const float* __restrict__ cond, const _Float16* __restrict__ WkT,
             const _Float16* __restrict__ WvT, _Float16* __restrict__ Kswz,
             _Float16* __restrict__ Vswz)
{
    const int tid = threadIdx.x;
    const int l = tid & 63, w = tid >> 6;
    const int lrow = l & 15, lk = l >> 4;
    const int h = blockIdx.x, b = blockIdx.y, which = blockIdx.z;
    const _Float16* WT = which ? WvT : WkT;
    const float* cb = cond + (size_t)b * M_CTX * 768;

    f32x4 acc[5];
#pragma unroll
    for (int i = 0; i < 5; ++i)
#pragma unroll
        for (int e = 0; e < 4; ++e) acc[i][e] = 0.f;

    const int n = h * 64 + w * 16 + lrow;
    for (int kk = 0; kk < 24; ++kk) {
        f16x8 bfrag = *(const f16x8*)(WT + (size_t)n * 768 + kk * 32 + lk * 8);
#pragma unroll
        for (int rt = 0; rt < 5; ++rt) {
            int m = rt * 16 + lrow;
            f16x8 afrag;
#pragma unroll
            for (int j = 0; j < 8; ++j) afrag[j] = (_Float16)0.f;
            if (m < M_CTX) {
                const float* a = cb + (size_t)m * 768 + kk * 32 + lk * 8;
                float4 f0 = *(const float4*)a;
                float4 f1 = *(const float4*)(a + 4);
                afrag[0] = f2h(f0.x); afrag[1] = f2h(f0.y);
                afrag[2] = f2h(f0.z); afrag[3] = f2h(f0.w);
                afrag[4] = f2h(f1.x); afrag[5] = f2h(f1.y);
                afrag[6] = f2h(f1.z); afrag[7] = f2h(f1.w);
            }
            acc[rt] = __builtin_amdgcn_mfma_f32_16x16x32_f16(afrag, bfrag, acc[rt], 0, 0, 0);
        }
    }

    const int bh = b * NH + h;
    const int d = w * 16 + lrow;
    const int dhi = d >> 3, dlo = d & 7;
    if (which == 0) {
        _Float16* Kb = Kswz + (size_t)bh * (M_PAD * 64);
#pragma unroll
        for (int rt = 0; rt < 5; ++rt)
#pragma unroll
            for (int r = 0; r < 4; ++r) {
                int m = rt * 16 + lk * 4 + r;
                Kb[m * 64 + ((dhi ^ (m & 7)) * 8) + dlo] = f2h(acc[rt][r]);
            }
#pragma unroll
        for (int r = 0; r < 4; ++r) {
            int m = 80 + lk * 4 + r;
            Kb[m * 64 + ((dhi ^ (m & 7)) * 8) + dlo] = (_Float16)0.f;
        }
    } else {
        _Float16* Vb = Vswz + (size_t)bh * (64 * 128);
#pragma unroll
        for (int rt = 0; rt < 5; ++rt)
#pragma unroll
            for (int r = 0; r < 4; ++r) {
                int m = rt * 16 + lk * 4 + r;
                Vb[d * 128 + (((m >> 3) ^ dlo) * 8) + (m & 7)] = f2h(acc[rt][r]);
            }
#pragma unroll
        for (int r = 0; r < 4; ++r) {
            int m = 80 + lk * 4 + r;
            Vb[d * 128 + (((m >> 3) ^ dlo) * 8) + (m & 7)] = (_Float16)0.f;
        }
    }
}

// ---------------------------------------------------------------------------
// gemm_skinny: C[65536][512] = A[65536][512] @ B (BT[512][512] f16 given).
// BM=64 x BN=512 (FULL N): the whole A-tile (64x512 f16 = 64KB) is staged to
// LDS ONCE (single barrier per block); B fragments are read DIRECT from
// global (B = 512KB, L2-resident, reused by all blocks). K-loop has ZERO
// barriers => loads pipeline freely across kt. 8 waves; wave w owns cols
// [w*64, w*64+64); acc[4][4]/wave. LDS slot-16B involution s' = s ^ (row&7)
// (proven R2/R8 pattern) => 2-way-max bank aliasing on ds_read_b128.
// QMODE 1: A = x fp32, staged via reg-cvt ds_write, C f16.
// QMODE 0: A f16, staged via gload16 w/ pre-swizzled source, C fp32 + bias.
// grid 1024 (= 8*128, bijective XCD chunking); block 512.
// ---------------------------------------------------------------------------
template<int QMODE>
__global__ __launch_bounds__(512)
void gemm_skinny(const void* __restrict__ Av, const _Float16* __restrict__ BT,
                 void* __restrict__ Cv, const float* __restrict__ bias)
{
    __shared__ _Float16 As[64 * 512];   // 64 KB; row r: slot s' holds A[r][s'^(r&7)]

    const int bid = blockIdx.x;
    const int wg = (bid & 7) * 128 + (bid >> 3);
    const size_t row0 = (size_t)wg * 64;

    const int tid = threadIdx.x;
    const int l = tid & 63, w = tid >> 6;          // 8 waves
    const int lrow = l & 15, lk = l >> 4;

    // ---- stage the A tile once ----
    if (QMODE) {
        // x fp32 -> f16, reg-staged. thread: row tid>>3, slots {i*8 + (tid&7)}
        // (low-3 bits vary per lane within a row => XOR'd slots spread banks).
        const float* X = (const float*)Av;
        const int row = tid >> 3;
        const int sb = tid & 7;
        const float* src = X + (row0 + row) * 512 + sb * 8;
        _Float16* dst = As + row * 512;
#pragma unroll
        for (int i = 0; i < 8; ++i) {
            float4 f0 = *(const float4*)(src + i * 64);
            float4 f1 = *(const float4*)(src + i * 64 + 4);
            f16x8 v;
            v[0] = f2h(f0.x); v[1] = f2h(f0.y); v[2] = f2h(f0.z); v[3] = f2h(f0.w);
            v[4] = f2h(f1.x); v[5] = f2h(f1.y); v[6] = f2h(f1.z); v[7] = f2h(f1.w);
            *(f16x8*)&dst[(((i * 8 + sb) ^ (row & 7)) * 8)] = v;
        }
    } else {
        // f16 A: one gload16 per row (64 lanes x 16B = full 1KB row, linear
        // LDS dest); source slot pre-XORed so LDS[r][l] = A[r][l^(r&7)].
        const _Float16* A = (const _Float16*)Av;
#pragma unroll
        for (int i = 0; i < 8; ++i) {
            const int row = w * 8 + i;
            gload16(A + (row0 + row) * 512 + ((l ^ (row & 7)) * 8), As + row * 512);
        }
    }
    __syncthreads();   // only barrier in the kernel

    // ---- barrier-free K-loop: A frags from LDS, B frags direct from L2 ----
    f32x4 acc[4][4];
#pragma unroll
    for (int i = 0; i < 4; ++i)
#pragma unroll
        for (int j = 0; j < 4; ++j)
#pragma unroll
            for (int e = 0; e < 4; ++e) acc[i][j][e] = 0.f;

    const _Float16* Ab = As + lrow * 512;
    const int sxor = lrow & 7;
    const _Float16* bb = BT + (size_t)(w * 64 + lrow) * 512 + lk * 8;

#pragma unroll 2
    for (int kt = 0; kt < 16; ++kt) {
        f16x8 af[4], bf[4];
#pragma unroll
        for (int nt = 0; nt < 4; ++nt)
            bf[nt] = *(const f16x8*)(bb + (size_t)nt * 16 * 512 + kt * 32);
#pragma unroll
        for (int mt = 0; mt < 4; ++mt)
            af[mt] = *(const f16x8*)(Ab + mt * 16 * 512 + (((kt * 4 + lk) ^ sxor) * 8));
#pragma unroll
        for (int mt = 0; mt < 4; ++mt)
#pragma unroll
            for (int nt = 0; nt < 4; ++nt)
                acc[mt][nt] = __builtin_amdgcn_mfma_f32_16x16x32_f16(af[mt], bf[nt], acc[mt][nt], 0, 0, 0);
    }

    // ---- epilogue ----
#pragma unroll
    for (int mt = 0; mt < 4; ++mt)
#pragma unroll
        for (int nt = 0; nt < 4; ++nt)
#pragma unroll
            for (int r = 0; r < 4; ++r) {
                size_t row = row0 + mt * 16 + lk * 4 + r;
                int col = w * 64 + nt * 16 + lrow;
                float v = acc[mt][nt][r];
                if (QMODE) {
                    ((_Float16*)Cv)[row * 512 + col] = f2h(v);
                } else {
                    ((float*)Cv)[row * 512 + col] = v + bias[col];
                }
            }
}

// ---------------------------------------------------------------------------
// attn (R3-proven): one block = one (b,h) x 256 Q-rows. K,V staged to LDS
// once via gload16 (swizzled layouts pre-baked in global). 4 waves x 64 rows.
// DPP softmax reductions, deferred 1/sum in the O epilogue.
// grid (16 chunks, 8 h, 16 b); block 256.
// ---------------------------------------------------------------------------
__global__ __launch_bounds__(256)
void attn(const _Float16* __restrict__ Q, const _Float16* __restrict__ Kswz,
          const _Float16* __restrict__ Vswz, _Float16* __restrict__ AO)
{
    __shared__ _Float16 Ks[M_PAD * 64];    // 12KB: row m, slot s at s^(m&7)
    __shared__ _Float16 Vs[64 * 128];      // 16KB: row d, slot s at s^(d&7)
    __shared__ _Float16 Pl[4][16][104];    // 13KB: per-wave P tile

    const int tid = threadIdx.x;
    const int l = tid & 63, w = tid >> 6;
    const int lrow = l & 15, lk = l >> 4;
    const int chunk = blockIdx.x, h = blockIdx.y, b = blockIdx.z;
    const int bh = b * NH + h;

    {
        const _Float16* Kg = Kswz + (size_t)bh * (M_PAD * 64);
        const _Float16* Vg = Vswz + (size_t)bh * (64 * 128);
#pragma unroll
        for (int i = 0; i < 3; ++i) {
            int c = w * 3 + i;
            gload16(Kg + c * 512 + l * 8, Ks + c * 512);
        }
#pragma unroll
        for (int i = 0; i < 4; ++i) {
            int c = w * 4 + i;
            gload16(Vg + c * 512 + l * 8, Vs + c * 512);
        }
    }

    const size_t row0 = (size_t)b * N_SEQ + chunk * 256 + w * 64;
    f16x8 af[4][2];
    {
        const _Float16* Qb = Q + (row0 + lrow) * 512 + h * 64 + lk * 8;
#pragma unroll
        for (int mt = 0; mt < 4; ++mt)
#pragma unroll
            for (int kk = 0; kk < 2; ++kk)
                af[mt][kk] = *(const f16x8*)(Qb + (size_t)mt * 16 * 512 + kk * 32);
    }

    for (int idx = l; idx < 256; idx += 64)
        Pl[w][idx >> 4][80 + (idx & 15)] = (_Float16)0.f;

    __syncthreads();   // drains vmcnt: K/V in LDS

    const bool m4ok = (lrow < 13);
    const int kswz = lrow & 7;

#pragma unroll
    for (int mt = 0; mt < 4; ++mt) {
        f32x4 s[5];
#pragma unroll
        for (int i = 0; i < 5; ++i)
#pragma unroll
            for (int e = 0; e < 4; ++e) s[i][e] = 0.f;
#pragma unroll
        for (int kk = 0; kk < 2; ++kk)
#pragma unroll
            for (int ct = 0; ct < 5; ++ct) {
                f16x8 kf = *(const f16x8*)&Ks[(ct * 16 + lrow) * 64 + (((kk * 4 + lk) ^ kswz) * 8)];
                s[ct] = __builtin_amdgcn_mfma_f32_16x16x32_f16(af[mt][kk], kf, s[ct], 0, 0, 0);
            }

        float rinv[4];
#pragma unroll
        for (int r = 0; r < 4; ++r) {
            float v0 = s[0][r], v1 = s[1][r], v2 = s[2][r], v3 = s[3][r], v4 = s[4][r];
            float mx = fmaxf(fmaxf(v0, v1), fmaxf(v2, v3));
            mx = fmaxf(mx, m4ok ? v4 : -1e30f);
            mx = rmax16(mx);
            float e0 = __expf(v0 - mx), e1 = __expf(v1 - mx);
            float e2 = __expf(v2 - mx), e3 = __expf(v3 - mx);
            float e4 = m4ok ? __expf(v4 - mx) : 0.f;
            float sum = ((e0 + e1) + (e2 + e3)) + e4;
            sum = rsum16(sum);
            rinv[r] = 1.0f / sum;
            int prow = lk * 4 + r;
            Pl[w][prow][lrow]      = f2h(e0);
            Pl[w][prow][16 + lrow] = f2h(e1);
            Pl[w][prow][32 + lrow] = f2h(e2);
            Pl[w][prow][48 + lrow] = f2h(e3);
            Pl[w][prow][64 + lrow] = f2h(e4);
        }

        f32x4 o[4];
#pragma unroll
        for (int i = 0; i < 4; ++i)
#pragma unroll
            for (int e2 = 0; e2 < 4; ++e2) o[i][e2] = 0.f;
#pragma unroll
        for (int kk = 0; kk < 3; ++kk) {
            f16x8 pa = *(const f16x8*)&Pl[w][lrow][kk * 32 + lk * 8];
#pragma unroll
            for (int ctd = 0; ctd < 4; ++ctd) {
                f16x8 vf = *(const f16x8*)&Vs[(ctd * 16 + lrow) * 128 + (((kk * 4 + lk) ^ kswz) * 8)];
                o[ctd] = __builtin_amdgcn_mfma_f32_16x16x32_f16(pa, vf, o[ctd], 0, 0, 0);
            }
        }

        const size_t rw = row0 + mt * 16 + lk * 4;
#pragma unroll
        for (int ctd = 0; ctd < 4; ++ctd)
#pragma unroll
            for (int r = 0; r < 4; ++r)
                AO[(rw + r) * 512 + h * 64 + ctd * 16 + lrow] = f2h(o[ctd][r] * rinv[r]);
    }
}

// ---------------------------------------------------------------------------
extern "C" void kernel_launch(void* const* d_in, const int* in_sizes, int n_in,
                              void* d_out, int out_size, void* d_ws, size_t ws_size,
                              hipStream_t stream)
{
    (void)in_sizes; (void)n_in; (void)out_size; (void)ws_size;
    const float* x    = (const float*)d_in[0];
    const float* cond = (const float*)d_in[1];
    const float* Wq   = (const float*)d_in[2];
    const float* Wk   = (const float*)d_in[3];
    const float* Wv   = (const float*)d_in[4];
    const float* Wo   = (const float*)d_in[5];
    const float* bo   = (const float*)d_in[6];

    char* ws = (char*)d_ws;
    _Float16* WqT  = (_Float16*)(ws);                        // 524288
    _Float16* WoT  = (_Float16*)(ws + 524288);               // 524288
    _Float16* Kswz = (_Float16*)(ws + 1048576);              // 1572864
    _Float16* Vswz = (_Float16*)(ws + 2621440);              // 2097152
    _Float16* AO   = (_Float16*)(ws + 4718592);              // 67108864
    // WkT/WvT alias AO's head: consumed by kv_proj BEFORE attn writes AO
    _Float16* WkT  = (_Float16*)(ws + 4718592);              // 786432
    _Float16* WvT  = (_Float16*)(ws + 4718592 + 786432);     // 786432
    // total ws: 71,827,456 bytes (same as previous rounds)
    _Float16* Qf   = (_Float16*)d_out;                       // f16 Q scratch in d_out
                                                             // (dead before gemm_o writes)

    prep<<<dim3(16, 24, 4), 256, 0, stream>>>(Wq, Wk, Wv, Wo, WqT, WkT, WvT, WoT);
    kv_proj<<<dim3(8, 16, 2), 256, 0, stream>>>(cond, WkT, WvT, Kswz, Vswz);
    gemm_skinny<1><<<dim3(1024), 512, 0, stream>>>(x, WqT, Qf, nullptr);
    attn<<<dim3(16, 8, 16), 256, 0, stream>>>(Qf, Kswz, Vswz, AO);
    gemm_skinny<0><<<dim3(1024), 512, 0, stream>>>(AO, WoT, (float*)d_out, bo);
}

// Round 11
// 227.093 us; speedup vs baseline: 1.4413x; 1.0972x over previous
//
#include <hip/hip_runtime.h>

typedef __attribute__((ext_vector_type(8))) _Float16 f16x8;
typedef __attribute__((ext_vector_type(4))) float f32x4;

#define B_SZ   16
#define N_SEQ  4096
#define M_CTX  77
#define M_PAD  96
#define NH     8

__device__ __forceinline__ _Float16 f2h(float x) { return (_Float16)x; }

// async global->LDS, 16B per lane. dst = wave-uniform base; HW writes
// dst + lane*16. Source address is per-lane (pre-swizzled by caller).
__device__ __forceinline__ void gload16(const void* g, void* l) {
    __builtin_amdgcn_global_load_lds(
        (const __attribute__((address_space(1))) unsigned int*)g,
        (__attribute__((address_space(3))) unsigned int*)l, 16, 0, 0);
}

#define BAR()    asm volatile("s_barrier" ::: "memory")
#define WAITV8() asm volatile("s_waitcnt vmcnt(8)" ::: "memory")

// ---- DPP 16-lane butterfly reductions (XOR masks {1,2,7,15} span 0..15) ----
template<int C>
__device__ __forceinline__ float dppf(float x) {
    union { float f; int i; } u, v;
    u.f = x;
    v.i = __builtin_amdgcn_mov_dpp(u.i, C, 0xF, 0xF, true);
    return v.f;
}
__device__ __forceinline__ float rmax16(float x) {
    x = fmaxf(x, dppf<0xB1>(x));
    x = fmaxf(x, dppf<0x4E>(x));
    x = fmaxf(x, dppf<0x141>(x));
    x = fmaxf(x, dppf<0x140>(x));
    return x;
}
__device__ __forceinline__ float rsum16(float x) {
    x += dppf<0xB1>(x);
    x += dppf<0x4E>(x);
    x += dppf<0x141>(x);
    x += dppf<0x140>(x);
    return x;
}

// ---------------------------------------------------------------------------
// convert: x fp32 -> x_h f16 (memory-bound, ~201 MB traffic) [R2-proven]
// ---------------------------------------------------------------------------
__global__ __launch_bounds__(256)
void convert(const float4* __restrict__ x, f16x8* __restrict__ xh, int n8)
{
    int idx = blockIdx.x * 256 + threadIdx.x;
    int stride = gridDim.x * 256;
    for (int i = idx; i < n8; i += stride) {
        float4 a = x[2 * i];
        float4 b = x[2 * i + 1];
        f16x8 o;
        o[0] = f2h(a.x); o[1] = f2h(a.y); o[2] = f2h(a.z); o[3] = f2h(a.w);
        o[4] = f2h(b.x); o[5] = f2h(b.y); o[6] = f2h(b.z); o[7] = f2h(b.w);
        xh[i] = o;
    }
}

// ---------------------------------------------------------------------------
// prep: W [K][512] fp32 -> WT [512][K] f16 (LDS-tiled transpose).
// Wq gets the 1/sqrt(D_HEAD)=0.125 softmax scale folded in.
// ---------------------------------------------------------------------------
__global__ __launch_bounds__(256)
void prep(const float* __restrict__ Wq, const float* __restrict__ Wk,
          const float* __restrict__ Wv, const float* __restrict__ Wo,
          _Float16* __restrict__ WqT, _Float16* __restrict__ WkT,
          _Float16* __restrict__ WvT, _Float16* __restrict__ WoT)
{
    __shared__ float t[32][33];
    const float* W; _Float16* WT; int K; float scale = 1.0f;
    switch (blockIdx.z) {
        case 0:  W = Wq; WT = WqT; K = 512; scale = 0.125f; break;
        case 1:  W = Wk; WT = WkT; K = 768; break;
        case 2:  W = Wv; WT = WvT; K = 768; break;
        default: W = Wo; WT = WoT; K = 512; break;
    }
    const int ky = blockIdx.y;
    if (ky * 32 >= K) return;
    const int nx = blockIdx.x;
    const int tr = threadIdx.x >> 5, tc = threadIdx.x & 31;
#pragma unroll
    for (int i = 0; i < 4; ++i) {
        int kr = tr + i * 8;
        t[kr][tc] = W[(size_t)(ky * 32 + kr) * 512 + nx * 32 + tc];
    }
    __syncthreads();
#pragma unroll
    for (int i = 0; i < 4; ++i) {
        int nr = tr + i * 8;
        WT[(size_t)(nx * 32 + nr) * K + ky * 32 + tc] = f2h(t[tc][nr] * scale);
    }
}

// ---------------------------------------------------------------------------
// kv_proj: writes K and V in BANK-SWIZZLED global layouts:
//   Kswz[bh][m][ ((d>>3)^(m&7))*8 + (d&7) ]   m in 0..95 (zeros >= 77)
//   Vswz[bh][d][ ((m>>3)^(d&7))*8 + (m&7) ]   rows of 128 f16 (slots 0..11 used)
// grid (8 h, 16 b, 2 kv); block 256 = 4 waves
// ---------------------------------------------------------------------------
__global__ __launch_bounds__(256)
void kv_proj(const float* __restrict__ cond, const _Float16* __restrict__ WkT,
             const _Float16* __restrict__ WvT, _Float16* __restrict__ Kswz,
             _Float16* __restrict__ Vswz)
{
    const int tid = threadIdx.x;
    const int l = tid & 63, w = tid >> 6;
    const int lrow = l & 15, lk = l >> 4;
    const int h = blockIdx.x, b = blockIdx.y, which = blockIdx.z;
    const _Float16* WT = which ? WvT : WkT;
    const float* cb = cond + (size_t)b * M_CTX * 768;

    f32x4 acc[5];
#pragma unroll
    for (int i = 0; i < 5; ++i)
#pragma unroll
        for (int e = 0; e < 4; ++e) acc[i][e] = 0.f;

    const int n = h * 64 + w * 16 + lrow;
    for (int kk = 0; kk < 24; ++kk) {
        f16x8 bfrag = *(const f16x8*)(WT + (size_t)n * 768 + kk * 32 + lk * 8);
#pragma unroll
        for (int rt = 0; rt < 5; ++rt) {
            int m = rt * 16 + lrow;
            f16x8 afrag;
#pragma unroll
            for (int j = 0; j < 8; ++j) afrag[j] = (_Float16)0.f;
            if (m < M_CTX) {
                const float* a = cb + (size_t)m * 768 + kk * 32 + lk * 8;
                float4 f0 = *(const float4*)a;
                float4 f1 = *(const float4*)(a + 4);
                afrag[0] = f2h(f0.x); afrag[1] = f2h(f0.y);
                afrag[2] = f2h(f0.z); afrag[3] = f2h(f0.w);
                afrag[4] = f2h(f1.x); afrag[5] = f2h(f1.y);
                afrag[6] = f2h(f1.z); afrag[7] = f2h(f1.w);
            }
            acc[rt] = __builtin_amdgcn_mfma_f32_16x16x32_f16(afrag, bfrag, acc[rt], 0, 0, 0);
        }
    }

    const int bh = b * NH + h;
    const int d = w * 16 + lrow;
    const int dhi = d >> 3, dlo = d & 7;
    if (which == 0) {
        _Float16* Kb = Kswz + (size_t)bh * (M_PAD * 64);
#pragma unroll
        for (int rt = 0; rt < 5; ++rt)
#pragma unroll
            for (int r = 0; r < 4; ++r) {
                int m = rt * 16 + lk * 4 + r;
                Kb[m * 64 + ((dhi ^ (m & 7)) * 8) + dlo] = f2h(acc[rt][r]);
            }
#pragma unroll
        for (int r = 0; r < 4; ++r) {
            int m = 80 + lk * 4 + r;
            Kb[m * 64 + ((dhi ^ (m & 7)) * 8) + dlo] = (_Float16)0.f;
        }
    } else {
        _Float16* Vb = Vswz + (size_t)bh * (64 * 128);
#pragma unroll
        for (int rt = 0; rt < 5; ++rt)
#pragma unroll
            for (int r = 0; r < 4; ++r) {
                int m = rt * 16 + lk * 4 + r;
                Vb[d * 128 + (((m >> 3) ^ dlo) * 8) + (m & 7)] = f2h(acc[rt][r]);
            }
#pragma unroll
        for (int r = 0; r < 4; ++r) {
            int m = 80 + lk * 4 + r;
            Vb[d * 128 + (((m >> 3) ^ dlo) * 8) + (m & 7)] = (_Float16)0.f;
        }
    }
}

// ---------------------------------------------------------------------------
// gemm_pipe: C[65536][512] = A[65536][512] @ B (BT[512][512] f16).
// Deep-pipelined ring: BM=256, BN=256, BK=32; 4 LDS slots (kt mod 4, 128KB);
// stage(kt+3) issued during kt => 3 K-steps of prefetch; per-iter
// vmcnt(8) (NEVER drains: queue at wait = stages kt+1,kt+2 = 8 loads, so
// kt's own loads -- older, counted in order -- are guaranteed landed) +
// ONE s_barrier. WAR: stage(kt+3) hits slot (kt-1)&3 whose readers finished
// (ds_read->MFMA dependency) before their iter-kt barrier. LDS rotation
// swizzle slot' = (kslot + row)&3: every 8-lane read batch = 4 slots x 2-way
// (free, m136); stage source pre-applies the inverse, LDS dest linear.
// 8 waves (2M x 4N), wave tile 128x64, acc[8][4]; 32 MFMA/kt in setprio(1).
// EMODE 0: C f16; EMODE 1: C fp32 + bias. grid 512 (=8*64 XCD-bijective).
// ---------------------------------------------------------------------------
template<int EMODE>
__global__ __launch_bounds__(512)
void gemm_pipe(const _Float16* __restrict__ A, const _Float16* __restrict__ BT,
               void* __restrict__ Cv, const float* __restrict__ bias)
{
    __shared__ _Float16 L[4 * 16384];   // 128KB: slot = [A 8192 f16 | B 8192 f16]

    const int bid = blockIdx.x;
    const int wg = (bid & 7) * 64 + (bid >> 3);
    const size_t row0 = (size_t)(wg >> 1) * 256;
    const int col0 = (wg & 1) * 256;

    const int tid = threadIdx.x;
    const int l = tid & 63, w = tid >> 6;          // 8 waves
    const int wy = w >> 2, wx = w & 3;             // 2M x 4N
    const int lrow = l & 15, lk = l >> 4;

    // ---- staging lane geometry (inverse rotation baked into source) ----
    const int srow  = l >> 2;                      // row within 16-row chunk
    const int sslot = ((l & 3) - srow) & 3;        // source k-slot for LDS slot l&3
    const _Float16* a_src = A  + (row0 + (size_t)(w * 32 + srow)) * 512 + sslot * 8;
    const _Float16* b_src = BT + ((size_t)col0 + w * 32 + srow) * 512 + sslot * 8;

    auto stage = [&](int t) {
        _Float16* dA = &L[(t & 3) * 16384 + w * 1024];   // rows w*32.., 16/chunk
        _Float16* dB = dA + 8192;
        const _Float16* sA = a_src + t * 32;
        const _Float16* sB = b_src + t * 32;
        gload16(sA,            dA);          // A rows w*32   .. +16
        gload16(sA + 16 * 512, dA + 512);    // A rows w*32+16.. +16
        gload16(sB,            dB);
        gload16(sB + 16 * 512, dB + 512);
    };

    f32x4 acc[8][4];
#pragma unroll
    for (int i = 0; i < 8; ++i)
#pragma unroll
        for (int j = 0; j < 4; ++j)
#pragma unroll
            for (int e = 0; e < 4; ++e) acc[i][j][e] = 0.f;

    // ---- prologue: 3 K-steps in flight ----
    stage(0); stage(1); stage(2);

    // read geometry: frag (row R, kslot lk) lives at R*32 + ((lk + R)&3)*8;
    // R&3 == lrow&3 for all mt/nt (16-multiples) => slot' = (lk+lrow)&3.
    const int rdoff = ((lk + lrow) & 3) * 8;
    const int aoff = (wy * 128 + lrow) * 32 + rdoff;          // + mt*512
    const int boff = 8192 + (wx * 64 + lrow) * 32 + rdoff;    // + nt*512

    for (int kt = 0; kt < 16; ++kt) {
        WAITV8();                         // kt's 4 loads landed (per wave)
        BAR();                            // ... collectively
        if (kt + 3 < 16) stage(kt + 3);   // into slot (kt-1)&3: readers done

        const _Float16* Lb = &L[(kt & 3) * 16384];
        f16x8 af[8], bf[4];
#pragma unroll
        for (int mt = 0; mt < 8; ++mt)
            af[mt] = *(const f16x8*)(Lb + aoff + mt * 512);
#pragma unroll
        for (int nt = 0; nt < 4; ++nt)
            bf[nt] = *(const f16x8*)(Lb + boff + nt * 512);

        __builtin_amdgcn_s_setprio(1);
#pragma unroll
        for (int mt = 0; mt < 8; ++mt)
#pragma unroll
            for (int nt = 0; nt < 4; ++nt)
                acc[mt][nt] = __builtin_amdgcn_mfma_f32_16x16x32_f16(af[mt], bf[nt], acc[mt][nt], 0, 0, 0);
        __builtin_amdgcn_s_setprio(0);
    }

    // ---- epilogue (R4-proven mapping) ----
#pragma unroll
    for (int mt = 0; mt < 8; ++mt)
#pragma unroll
        for (int nt = 0; nt < 4; ++nt)
#pragma unroll
            for (int r = 0; r < 4; ++r) {
                size_t row = row0 + wy * 128 + mt * 16 + lk * 4 + r;
                int col = col0 + wx * 64 + nt * 16 + lrow;
                float v = acc[mt][nt][r];
                if (EMODE == 0) {
                    ((_Float16*)Cv)[row * 512 + col] = f2h(v);
                } else {
                    ((float*)Cv)[row * 512 + col] = v + bias[col];
                }
            }
}

// ---------------------------------------------------------------------------
// attn (R3-proven): one block = one (b,h) x 256 Q-rows. K,V staged to LDS
// once via gload16 (swizzled layouts pre-baked in global). 4 waves x 64 rows.
// DPP softmax reductions, deferred 1/sum in the O epilogue.
// grid (16 chunks, 8 h, 16 b); block 256.
// ---------------------------------------------------------------------------
__global__ __launch_bounds__(256)
void attn(const _Float16* __restrict__ Q, const _Float16* __restrict__ Kswz,
          const _Float16* __restrict__ Vswz, _Float16* __restrict__ AO)
{
    __shared__ _Float16 Ks[M_PAD * 64];    // 12KB: row m, slot s at s^(m&7)
    __shared__ _Float16 Vs[64 * 128];      // 16KB: row d, slot s at s^(d&7)
    __shared__ _Float16 Pl[4][16][104];    // 13KB: per-wave P tile

    const int tid = threadIdx.x;
    const int l = tid & 63, w = tid >> 6;
    const int lrow = l & 15, lk = l >> 4;
    const int chunk = blockIdx.x, h = blockIdx.y, b = blockIdx.z;
    const int bh = b * NH + h;

    {
        const _Float16* Kg = Kswz + (size_t)bh * (M_PAD * 64);
        const _Float16* Vg = Vswz + (size_t)bh * (64 * 128);
#pragma unroll
        for (int i = 0; i < 3; ++i) {
            int c = w * 3 + i;
            gload16(Kg + c * 512 + l * 8, Ks + c * 512);
        }
#pragma unroll
        for (int i = 0; i < 4; ++i) {
            int c = w * 4 + i;
            gload16(Vg + c * 512 + l * 8, Vs + c * 512);
        }
    }

    const size_t row0 = (size_t)b * N_SEQ + chunk * 256 + w * 64;
    f16x8 af[4][2];
    {
        const _Float16* Qb = Q + (row0 + lrow) * 512 + h * 64 + lk * 8;
#pragma unroll
        for (int mt = 0; mt < 4; ++mt)
#pragma unroll
            for (int kk = 0; kk < 2; ++kk)
                af[mt][kk] = *(const f16x8*)(Qb + (size_t)mt * 16 * 512 + kk * 32);
    }

    for (int idx = l; idx < 256; idx += 64)
        Pl[w][idx >> 4][80 + (idx & 15)] = (_Float16)0.f;

    __syncthreads();   // drains vmcnt: K/V in LDS

    const bool m4ok = (lrow < 13);
    const int kswz = lrow & 7;

#pragma unroll
    for (int mt = 0; mt < 4; ++mt) {
        f32x4 s[5];
#pragma unroll
        for (int i = 0; i < 5; ++i)
#pragma unroll
            for (int e = 0; e < 4; ++e) s[i][e] = 0.f;
#pragma unroll
        for (int kk = 0; kk < 2; ++kk)
#pragma unroll
            for (int ct = 0; ct < 5; ++ct) {
                f16x8 kf = *(const f16x8*)&Ks[(ct * 16 + lrow) * 64 + (((kk * 4 + lk) ^ kswz) * 8)];
                s[ct] = __builtin_amdgcn_mfma_f32_16x16x32_f16(af[mt][kk], kf, s[ct], 0, 0, 0);
            }

        float rinv[4];
#pragma unroll
        for (int r = 0; r < 4; ++r) {
            float v0 = s[0][r], v1 = s[1][r], v2 = s[2][r], v3 = s[3][r], v4 = s[4][r];
            float mx = fmaxf(fmaxf(v0, v1), fmaxf(v2, v3));
            mx = fmaxf(mx, m4ok ? v4 : -1e30f);
            mx = rmax16(mx);
            float e0 = __expf(v0 - mx), e1 = __expf(v1 - mx);
            float e2 = __expf(v2 - mx), e3 = __expf(v3 - mx);
            float e4 = m4ok ? __expf(v4 - mx) : 0.f;
            float sum = ((e0 + e1) + (e2 + e3)) + e4;
            sum = rsum16(sum);
            rinv[r] = 1.0f / sum;
            int prow = lk * 4 + r;
            Pl[w][prow][lrow]      = f2h(e0);
            Pl[w][prow][16 + lrow] = f2h(e1);
            Pl[w][prow][32 + lrow] = f2h(e2);
            Pl[w][prow][48 + lrow] = f2h(e3);
            Pl[w][prow][64 + lrow] = f2h(e4);
        }

        f32x4 o[4];
#pragma unroll
        for (int i = 0; i < 4; ++i)
#pragma unroll
            for (int e2 = 0; e2 < 4; ++e2) o[i][e2] = 0.f;
#pragma unroll
        for (int kk = 0; kk < 3; ++kk) {
            f16x8 pa = *(const f16x8*)&Pl[w][lrow][kk * 32 + lk * 8];
#pragma unroll
            for (int ctd = 0; ctd < 4; ++ctd) {
                f16x8 vf = *(const f16x8*)&Vs[(ctd * 16 + lrow) * 128 + (((kk * 4 + lk) ^ kswz) * 8)];
                o[ctd] = __builtin_amdgcn_mfma_f32_16x16x32_f16(pa, vf, o[ctd], 0, 0, 0);
            }
        }

        const size_t rw = row0 + mt * 16 + lk * 4;
#pragma unroll
        for (int ctd = 0; ctd < 4; ++ctd)
#pragma unroll
            for (int r = 0; r < 4; ++r)
                AO[(rw + r) * 512 + h * 64 + ctd * 16 + lrow] = f2h(o[ctd][r] * rinv[r]);
    }
}

// ---------------------------------------------------------------------------
extern "C" void kernel_launch(void* const* d_in, const int* in_sizes, int n_in,
                              void* d_out, int out_size, void* d_ws, size_t ws_size,
                              hipStream_t stream)
{
    (void)in_sizes; (void)n_in; (void)out_size; (void)ws_size;
    const float* x    = (const float*)d_in[0];
    const float* cond = (const float*)d_in[1];
    const float* Wq   = (const float*)d_in[2];
    const float* Wk   = (const float*)d_in[3];
    const float* Wv   = (const float*)d_in[4];
    const float* Wo   = (const float*)d_in[5];
    const float* bo   = (const float*)d_in[6];

    char* ws = (char*)d_ws;
    _Float16* WqT  = (_Float16*)(ws);                        // 524288
    _Float16* WoT  = (_Float16*)(ws + 524288);               // 524288
    _Float16* Kswz = (_Float16*)(ws + 1048576);              // 1572864
    _Float16* Vswz = (_Float16*)(ws + 2621440);              // 2097152
    _Float16* xh   = (_Float16*)(ws + 4718592);              // 67108864
    // WkT/WvT alias xh's head: consumed by kv_proj BEFORE convert overwrites
    _Float16* WkT  = (_Float16*)(ws + 4718592);              // 786432
    _Float16* WvT  = (_Float16*)(ws + 4718592 + 786432);     // 786432
    _Float16* AO   = xh;                                     // xh dead after gemm_q
    // total ws: 71,827,456 bytes (same as previous rounds)
    _Float16* Qf   = (_Float16*)d_out;                       // dead before gemm_o writes

    prep<<<dim3(16, 24, 4), 256, 0, stream>>>(Wq, Wk, Wv, Wo, WqT, WkT, WvT, WoT);
    kv_proj<<<dim3(8, 16, 2), 256, 0, stream>>>(cond, WkT, WvT, Kswz, Vswz);
    convert<<<dim3(2048), 256, 0, stream>>>((const float4*)x, (f16x8*)xh, 16 * 4096 * 512 / 8);
    gemm_pipe<0><<<dim3(512), 512, 0, stream>>>(xh, WqT, Qf, nullptr);
    attn<<<dim3(16, 8, 16), 256, 0, stream>>>(Qf, Kswz, Vswz, AO);
    gemm_pipe<1><<<dim3(512), 512, 0, stream>>>(AO, WoT, d_out, bo);
}